// Round 1
// baseline (1181.951 us; speedup 1.0000x reference)
//
#include <hip/hip_runtime.h>

#define NROWS 4096
#define HID 64

// ---------------- kernel 1: x = in@emb_w+b ; q = x@q_w+b ; k = x@k_w+b ----
__global__ __launch_bounds__(64) void k_embed(
    const float* __restrict__ inp, const float* __restrict__ emb_w,
    const float* __restrict__ emb_b, const float* __restrict__ q_w,
    const float* __restrict__ q_b, const float* __restrict__ k_w,
    const float* __restrict__ k_b, float* __restrict__ q, float* __restrict__ k) {
  int row = blockIdx.x;
  int t = threadIdx.x;  // 64 threads
  __shared__ float in_s[8];
  __shared__ float x_s[64];
  if (t < 8) in_s[t] = inp[row * 8 + t];
  __syncthreads();
  float acc = emb_b[t];
#pragma unroll
  for (int i = 0; i < 8; ++i) acc += in_s[i] * emb_w[i * 64 + t];
  x_s[t] = acc;
  __syncthreads();
  float qa = q_b[t], ka = k_b[t];
#pragma unroll
  for (int i = 0; i < 64; ++i) {
    float xv = x_s[i];
    qa += xv * q_w[i * 64 + t];
    ka += xv * k_w[i * 64 + t];
  }
  q[row * 64 + t] = qa;
  k[row * 64 + t] = ka;
}

// ---------------- kernel 2: raw scores + online softmax row stats ---------
// 8 rows per block, 256 threads. thread t: row r=t>>5, 32-lane group over cols.
__global__ __launch_bounds__(256) void k_scores(
    const float* __restrict__ q, const float* __restrict__ k,
    float* __restrict__ S, float* __restrict__ rowmax, float* __restrict__ rowsum) {
  int r0 = blockIdx.x * 8;
  int t = threadIdx.x;
  int r = t >> 5;
  int lane = t & 31;
  int row = r0 + r;
  __shared__ float qs[8][64];
  for (int i = t; i < 512; i += 256) qs[i >> 6][i & 63] = q[r0 * 64 + i];
  __syncthreads();
  float m = -1e30f, l = 0.f;
  for (int tile = 0; tile < 16; ++tile) {
#pragma unroll
    for (int s = 0; s < 8; ++s) {
      int col = tile * 256 + s * 32 + lane;
      const float4* kp = (const float4*)(k + (size_t)col * 64);
      float acc = 0.f;
#pragma unroll
      for (int c = 0; c < 16; ++c) {
        float4 kv = kp[c];
        acc += kv.x * qs[r][4 * c] + kv.y * qs[r][4 * c + 1] +
               kv.z * qs[r][4 * c + 2] + kv.w * qs[r][4 * c + 3];
      }
      float sc = acc * 0.125f;
      S[(size_t)row * NROWS + col] = sc;
      float nm = fmaxf(m, sc);
      l = l * __expf(m - nm) + __expf(sc - nm);
      m = nm;
    }
  }
  // combine (m,l) across the 32-lane group
  for (int off = 16; off > 0; off >>= 1) {
    float m2 = __shfl_xor(m, off, 32);
    float l2 = __shfl_xor(l, off, 32);
    float nm = fmaxf(m, m2);
    l = l * __expf(m - nm) + l2 * __expf(m2 - nm);
    m = nm;
  }
  if (lane == 0) {
    rowmax[row] = m;
    rowsum[row] = l;
  }
}

// ---------------- kernel 3: in-place normalize S -> attn ------------------
__global__ __launch_bounds__(256) void k_norm(float* __restrict__ S,
                                              const float* __restrict__ rowmax,
                                              const float* __restrict__ rowsum) {
  size_t i4 = (size_t)blockIdx.x * 256 + threadIdx.x;  // float4 index
  int row = (int)(i4 >> 10);                           // 1024 float4 per row
  float m = rowmax[row];
  float linv = 1.0f / rowsum[row];
  float4 v = ((float4*)S)[i4];
  v.x = __expf(v.x - m) * linv;
  v.y = __expf(v.y - m) * linv;
  v.z = __expf(v.z - m) * linv;
  v.w = __expf(v.w - m) * linv;
  ((float4*)S)[i4] = v;
}

// ---------------- kernel 4: one asym conv layer + leaky relu --------------
// out(i,j) = leaky( w1·in(i,j-1..j+1) + w2·in(i-1..i+1,j) )
__global__ __launch_bounds__(256) void k_conv(
    const float* __restrict__ in, float* __restrict__ out,
    const float* __restrict__ w1p, const float* __restrict__ w2p,
    const float* __restrict__ ap, int layer) {
  float w10 = w1p[layer * 3], w11 = w1p[layer * 3 + 1], w12 = w1p[layer * 3 + 2];
  float w20 = w2p[layer * 3], w21 = w2p[layer * 3 + 1], w22 = w2p[layer * 3 + 2];
  float a = ap[layer];
  int j = blockIdx.x * 256 + threadIdx.x;
  int i0 = blockIdx.y * 8;
  float vm = (i0 > 0) ? in[(size_t)(i0 - 1) * NROWS + j] : 0.f;
  float vc = in[(size_t)i0 * NROWS + j];
#pragma unroll
  for (int rr = 0; rr < 8; ++rr) {
    int i = i0 + rr;
    float vp = (i + 1 < NROWS) ? in[(size_t)(i + 1) * NROWS + j] : 0.f;
    float lft = (j > 0) ? in[(size_t)i * NROWS + j - 1] : 0.f;
    float rgt = (j < NROWS - 1) ? in[(size_t)i * NROWS + j + 1] : 0.f;
    float o = w10 * lft + w11 * vc + w12 * rgt + w20 * vm + w21 * vc + w22 * vp;
    out[(size_t)i * NROWS + j] = (o >= 0.f) ? o : a * o;
    vm = vc;
    vc = vp;
  }
}

// ---------------- kernel 5: calc = (conv>0)*attn @ o ----------------------
// recomputes scores from q,k + row stats (raw S buffer was consumed by conv)
__global__ __launch_bounds__(256) void k_calc(
    const float* __restrict__ q, const float* __restrict__ k,
    const float* __restrict__ conv, const float* __restrict__ inp,
    const float* __restrict__ rowmax, const float* __restrict__ rowsum,
    float* __restrict__ calc) {
  int r0 = blockIdx.x * 8;
  int t = threadIdx.x;
  int r = t >> 5;
  int lane = t & 31;
  int row = r0 + r;
  __shared__ float qs[8][64];
  for (int i = t; i < 512; i += 256) qs[i >> 6][i & 63] = q[r0 * 64 + i];
  __syncthreads();
  float m = rowmax[row];
  float linv = 1.0f / rowsum[row];
  float a0 = 0.f, a1 = 0.f, a2 = 0.f, a3 = 0.f;
  for (int tile = 0; tile < 16; ++tile) {
#pragma unroll
    for (int s = 0; s < 8; ++s) {
      int col = tile * 256 + s * 32 + lane;
      float cf = conv[(size_t)row * NROWS + col];
      if (cf > 0.f) {
        const float4* kp = (const float4*)(k + (size_t)col * 64);
        float acc = 0.f;
#pragma unroll
        for (int c = 0; c < 16; ++c) {
          float4 kv = kp[c];
          acc += kv.x * qs[r][4 * c] + kv.y * qs[r][4 * c + 1] +
                 kv.z * qs[r][4 * c + 2] + kv.w * qs[r][4 * c + 3];
        }
        float w = __expf(acc * 0.125f - m) * linv;
        float4 ov = *(const float4*)(inp + (size_t)col * 8 + 4);
        a0 += w * ov.x;
        a1 += w * ov.y;
        a2 += w * ov.z;
        a3 += w * ov.w;
      }
    }
  }
  for (int off = 16; off > 0; off >>= 1) {
    a0 += __shfl_xor(a0, off, 32);
    a1 += __shfl_xor(a1, off, 32);
    a2 += __shfl_xor(a2, off, 32);
    a3 += __shfl_xor(a3, off, 32);
  }
  if (lane == 0) {
    calc[row * 4 + 0] = a0;
    calc[row * 4 + 1] = a1;
    calc[row * 4 + 2] = a2;
    calc[row * 4 + 3] = a3;
  }
}

// ---------------- kernel 6: gcn + mlp head --------------------------------
__global__ __launch_bounds__(64) void k_head(
    const float* __restrict__ calc, const float* __restrict__ gcn_w,
    const float* __restrict__ gcn_b, const float* __restrict__ gcn_a,
    const float* __restrict__ w1, const float* __restrict__ b1,
    const float* __restrict__ w2, const float* __restrict__ b2,
    float* __restrict__ out) {
  int row = blockIdx.x;
  int t = threadIdx.x;  // 64
  __shared__ float c4[4];
  __shared__ float gs[64];
  __shared__ float ms[32];
  if (t < 4) c4[t] = calc[row * 4 + t];
  __syncthreads();
  float g = gcn_b[t];
#pragma unroll
  for (int d = 0; d < 4; ++d) g += c4[d] * gcn_w[d * 64 + t];
  float ga = gcn_a[0];
  gs[t] = (g >= 0.f) ? g : ga * g;
  __syncthreads();
  if (t < 32) {
    float mm = b1[t];
#pragma unroll
    for (int i = 0; i < 64; ++i) mm += gs[i] * w1[i * 32 + t];
    ms[t] = fmaxf(mm, 0.f);
  }
  __syncthreads();
  if (t < 4) {
    float o = b2[t];
#pragma unroll
    for (int i = 0; i < 32; ++i) o += ms[i] * w2[i * 4 + t];
    out[row * 4 + t] = o;
  }
}

extern "C" void kernel_launch(void* const* d_in, const int* in_sizes, int n_in,
                              void* d_out, int out_size, void* d_ws, size_t ws_size,
                              hipStream_t stream) {
  (void)in_sizes; (void)n_in; (void)out_size; (void)ws_size;
  const float* inp    = (const float*)d_in[0];
  const float* emb_w  = (const float*)d_in[1];
  const float* emb_b  = (const float*)d_in[2];
  const float* q_w    = (const float*)d_in[3];
  const float* q_b    = (const float*)d_in[4];
  const float* k_w    = (const float*)d_in[5];
  const float* k_b    = (const float*)d_in[6];
  const float* conv_w1 = (const float*)d_in[7];
  const float* conv_w2 = (const float*)d_in[8];
  const float* conv_a  = (const float*)d_in[9];
  const float* gcn_w  = (const float*)d_in[10];
  const float* gcn_b  = (const float*)d_in[11];
  const float* gcn_a  = (const float*)d_in[12];
  const float* mlp_w1 = (const float*)d_in[13];
  const float* mlp_b1 = (const float*)d_in[14];
  const float* mlp_w2 = (const float*)d_in[15];
  const float* mlp_b2 = (const float*)d_in[16];
  float* out = (float*)d_out;

  const size_t NN = (size_t)NROWS * NROWS;
  float* A      = (float*)d_ws;        // 4096^2
  float* B      = A + NN;              // 4096^2
  float* q      = B + NN;              // 4096*64
  float* k      = q + (size_t)NROWS * HID;
  float* rowmax = k + (size_t)NROWS * HID;
  float* rowsum = rowmax + NROWS;
  float* calc   = rowsum + NROWS;      // 4096*4

  k_embed<<<NROWS, 64, 0, stream>>>(inp, emb_w, emb_b, q_w, q_b, k_w, k_b, q, k);
  k_scores<<<NROWS / 8, 256, 0, stream>>>(q, k, A, rowmax, rowsum);
  k_norm<<<(NN / 4) / 256, 256, 0, stream>>>(A, rowmax, rowsum);

  float* cin = A;
  float* cout = B;
  for (int layer = 0; layer < 10; ++layer) {
    k_conv<<<dim3(NROWS / 256, NROWS / 8), 256, 0, stream>>>(cin, cout, conv_w1,
                                                             conv_w2, conv_a, layer);
    float* tmp = cin; cin = cout; cout = tmp;
  }
  // after 10 swaps, final conv output is back in A (== cin)

  k_calc<<<NROWS / 8, 256, 0, stream>>>(q, k, cin, inp, rowmax, rowsum, calc);
  k_head<<<NROWS, 64, 0, stream>>>(calc, gcn_w, gcn_b, gcn_a, mlp_w1, mlp_b1,
                                   mlp_w2, mlp_b2, out);
}

// Round 2
// 1059.148 us; speedup vs baseline: 1.1159x; 1.1159x over previous
//
#include <hip/hip_runtime.h>

#define NROWS 4096
#define HID 64

// ---------------- kernel 1: x=in@emb_w+b; q=x@q_w+b; kT=(x@k_w+b)^T; o pack
__global__ __launch_bounds__(64) void k_embed(
    const float* __restrict__ inp, const float* __restrict__ emb_w,
    const float* __restrict__ emb_b, const float* __restrict__ q_w,
    const float* __restrict__ q_b, const float* __restrict__ k_w,
    const float* __restrict__ k_b, float* __restrict__ q,
    float* __restrict__ kT, float* __restrict__ opk) {
  int row = blockIdx.x;
  int t = threadIdx.x;  // 64 threads
  __shared__ float in_s[8];
  __shared__ float x_s[64];
  if (t < 8) in_s[t] = inp[row * 8 + t];
  __syncthreads();
  float acc = emb_b[t];
#pragma unroll
  for (int i = 0; i < 8; ++i) acc += in_s[i] * emb_w[i * 64 + t];
  x_s[t] = acc;
  __syncthreads();
  float qa = q_b[t], ka = k_b[t];
#pragma unroll
  for (int i = 0; i < 64; ++i) {
    float xv = x_s[i];
    qa += xv * q_w[i * 64 + t];
    ka += xv * k_w[i * 64 + t];
  }
  q[row * 64 + t] = qa;
  kT[(size_t)t * NROWS + row] = ka;  // transposed store (scattered but tiny)
  if (t < 4) opk[row * 4 + t] = inp[row * 8 + 4 + t];
}

// ---------------- kernel 2: raw scores (coalesced kT) + row max -----------
// 512 blocks x 256 thr. Thread: p = t>>6 (wave), g = t&63.
// Rows rowA=r0+p, rowB=r0+p+4 (q rows in registers). Cols: tile*256 + g*4.
__global__ __launch_bounds__(256) void k_scores(
    const float* __restrict__ q, const float* __restrict__ kT,
    float* __restrict__ S, float* __restrict__ rowmax) {
  int t = threadIdx.x;
  int p = t >> 6;
  int g = t & 63;
  int r0 = blockIdx.x * 8;
  int rowA = r0 + p, rowB = rowA + 4;
  float qa[64], qb[64];
  const float4* qA = (const float4*)(q + (size_t)rowA * 64);
  const float4* qB = (const float4*)(q + (size_t)rowB * 64);
#pragma unroll
  for (int i = 0; i < 16; ++i) {
    float4 v = qA[i];
    qa[4 * i] = v.x; qa[4 * i + 1] = v.y; qa[4 * i + 2] = v.z; qa[4 * i + 3] = v.w;
    float4 w = qB[i];
    qb[4 * i] = w.x; qb[4 * i + 1] = w.y; qb[4 * i + 2] = w.z; qb[4 * i + 3] = w.w;
  }
  float mA = -1e30f, mB = -1e30f;
  for (int tile = 0; tile < 16; ++tile) {
    int colb = tile * 256 + g * 4;
    float aA0 = 0.f, aA1 = 0.f, aA2 = 0.f, aA3 = 0.f;
    float aB0 = 0.f, aB1 = 0.f, aB2 = 0.f, aB3 = 0.f;
#pragma unroll
    for (int c = 0; c < 64; ++c) {
      float4 kv = *(const float4*)(kT + (size_t)c * NROWS + colb);
      aA0 += qa[c] * kv.x; aA1 += qa[c] * kv.y; aA2 += qa[c] * kv.z; aA3 += qa[c] * kv.w;
      aB0 += qb[c] * kv.x; aB1 += qb[c] * kv.y; aB2 += qb[c] * kv.z; aB3 += qb[c] * kv.w;
    }
    aA0 *= 0.125f; aA1 *= 0.125f; aA2 *= 0.125f; aA3 *= 0.125f;
    aB0 *= 0.125f; aB1 *= 0.125f; aB2 *= 0.125f; aB3 *= 0.125f;
    float4 sA = {aA0, aA1, aA2, aA3};
    float4 sB = {aB0, aB1, aB2, aB3};
    *(float4*)(S + (size_t)rowA * NROWS + colb) = sA;
    *(float4*)(S + (size_t)rowB * NROWS + colb) = sB;
    mA = fmaxf(mA, fmaxf(fmaxf(aA0, aA1), fmaxf(aA2, aA3)));
    mB = fmaxf(mB, fmaxf(fmaxf(aB0, aB1), fmaxf(aB2, aB3)));
  }
#pragma unroll
  for (int off = 32; off > 0; off >>= 1) {
    mA = fmaxf(mA, __shfl_xor(mA, off, 64));
    mB = fmaxf(mB, __shfl_xor(mB, off, 64));
  }
  if (g == 0) {
    rowmax[rowA] = mA;
    rowmax[rowB] = mB;
  }
}

// ---------------- kernel 3: softmax normalize in place, rows per block ----
// 512 blocks x 256 thr; 8 rows/block; 32-lane group per row (within a wave).
__global__ __launch_bounds__(256) void k_norm(float* __restrict__ S,
                                              const float* __restrict__ rowmax,
                                              float* __restrict__ rowsum) {
  int t = threadIdx.x;
  int r = t >> 5;
  int lane = t & 31;
  int row = blockIdx.x * 8 + r;
  float m = rowmax[row];
  float4* Sp = (float4*)(S + (size_t)row * NROWS);
  float l = 0.f;
  for (int i = lane; i < 1024; i += 32) {
    float4 v = Sp[i];
    v.x = __expf(v.x - m); v.y = __expf(v.y - m);
    v.z = __expf(v.z - m); v.w = __expf(v.w - m);
    Sp[i] = v;
    l += v.x + v.y + v.z + v.w;
  }
#pragma unroll
  for (int off = 16; off > 0; off >>= 1) l += __shfl_xor(l, off, 32);
  float linv = 1.0f / l;
  for (int i = lane; i < 1024; i += 32) {
    float4 v = Sp[i];
    v.x *= linv; v.y *= linv; v.z *= linv; v.w *= linv;
    Sp[i] = v;
  }
  if (lane == 0) rowsum[row] = l;
}

// ---------------- kernel 4: one asym conv layer + leaky relu --------------
__global__ __launch_bounds__(256) void k_conv(
    const float* __restrict__ in, float* __restrict__ out,
    const float* __restrict__ w1p, const float* __restrict__ w2p,
    const float* __restrict__ ap, int layer) {
  float w10 = w1p[layer * 3], w11 = w1p[layer * 3 + 1], w12 = w1p[layer * 3 + 2];
  float w20 = w2p[layer * 3], w21 = w2p[layer * 3 + 1], w22 = w2p[layer * 3 + 2];
  float a = ap[layer];
  int j = blockIdx.x * 256 + threadIdx.x;
  int i0 = blockIdx.y * 8;
  float vm = (i0 > 0) ? in[(size_t)(i0 - 1) * NROWS + j] : 0.f;
  float vc = in[(size_t)i0 * NROWS + j];
#pragma unroll
  for (int rr = 0; rr < 8; ++rr) {
    int i = i0 + rr;
    float vp = (i + 1 < NROWS) ? in[(size_t)(i + 1) * NROWS + j] : 0.f;
    float lft = (j > 0) ? in[(size_t)i * NROWS + j - 1] : 0.f;
    float rgt = (j < NROWS - 1) ? in[(size_t)i * NROWS + j + 1] : 0.f;
    float o = w10 * lft + w11 * vc + w12 * rgt + w20 * vm + w21 * vc + w22 * vp;
    out[(size_t)i * NROWS + j] = (o >= 0.f) ? o : a * o;
    vm = vc;
    vc = vp;
  }
}

// ---------------- kernel 5: calc = (conv>0)*softmax(s) @ o (recompute) ----
// Same mapping as k_scores; conv/o loads coalesced; scores recomputed from kT.
__global__ __launch_bounds__(256) void k_calc(
    const float* __restrict__ q, const float* __restrict__ kT,
    const float* __restrict__ conv, const float* __restrict__ opk,
    const float* __restrict__ rowmax, const float* __restrict__ rowsum,
    float* __restrict__ calc) {
  int t = threadIdx.x;
  int p = t >> 6;
  int g = t & 63;
  int r0 = blockIdx.x * 8;
  int rowA = r0 + p, rowB = rowA + 4;
  float qa[64], qb[64];
  const float4* qA = (const float4*)(q + (size_t)rowA * 64);
  const float4* qB = (const float4*)(q + (size_t)rowB * 64);
#pragma unroll
  for (int i = 0; i < 16; ++i) {
    float4 v = qA[i];
    qa[4 * i] = v.x; qa[4 * i + 1] = v.y; qa[4 * i + 2] = v.z; qa[4 * i + 3] = v.w;
    float4 w = qB[i];
    qb[4 * i] = w.x; qb[4 * i + 1] = w.y; qb[4 * i + 2] = w.z; qb[4 * i + 3] = w.w;
  }
  float mA = rowmax[rowA], liA = 1.0f / rowsum[rowA];
  float mB = rowmax[rowB], liB = 1.0f / rowsum[rowB];
  float acA0 = 0.f, acA1 = 0.f, acA2 = 0.f, acA3 = 0.f;
  float acB0 = 0.f, acB1 = 0.f, acB2 = 0.f, acB3 = 0.f;
  for (int tile = 0; tile < 16; ++tile) {
    int colb = tile * 256 + g * 4;
    float aA0 = 0.f, aA1 = 0.f, aA2 = 0.f, aA3 = 0.f;
    float aB0 = 0.f, aB1 = 0.f, aB2 = 0.f, aB3 = 0.f;
#pragma unroll
    for (int c = 0; c < 64; ++c) {
      float4 kv = *(const float4*)(kT + (size_t)c * NROWS + colb);
      aA0 += qa[c] * kv.x; aA1 += qa[c] * kv.y; aA2 += qa[c] * kv.z; aA3 += qa[c] * kv.w;
      aB0 += qb[c] * kv.x; aB1 += qb[c] * kv.y; aB2 += qb[c] * kv.z; aB3 += qb[c] * kv.w;
    }
    float4 cA = *(const float4*)(conv + (size_t)rowA * NROWS + colb);
    float4 cB = *(const float4*)(conv + (size_t)rowB * NROWS + colb);
    float4 o0 = *(const float4*)(opk + (size_t)(colb + 0) * 4);
    float4 o1 = *(const float4*)(opk + (size_t)(colb + 1) * 4);
    float4 o2 = *(const float4*)(opk + (size_t)(colb + 2) * 4);
    float4 o3 = *(const float4*)(opk + (size_t)(colb + 3) * 4);
    float wA0 = (cA.x > 0.f) ? __expf(aA0 * 0.125f - mA) * liA : 0.f;
    float wA1 = (cA.y > 0.f) ? __expf(aA1 * 0.125f - mA) * liA : 0.f;
    float wA2 = (cA.z > 0.f) ? __expf(aA2 * 0.125f - mA) * liA : 0.f;
    float wA3 = (cA.w > 0.f) ? __expf(aA3 * 0.125f - mA) * liA : 0.f;
    float wB0 = (cB.x > 0.f) ? __expf(aB0 * 0.125f - mB) * liB : 0.f;
    float wB1 = (cB.y > 0.f) ? __expf(aB1 * 0.125f - mB) * liB : 0.f;
    float wB2 = (cB.z > 0.f) ? __expf(aB2 * 0.125f - mB) * liB : 0.f;
    float wB3 = (cB.w > 0.f) ? __expf(aB3 * 0.125f - mB) * liB : 0.f;
    acA0 += wA0 * o0.x + wA1 * o1.x + wA2 * o2.x + wA3 * o3.x;
    acA1 += wA0 * o0.y + wA1 * o1.y + wA2 * o2.y + wA3 * o3.y;
    acA2 += wA0 * o0.z + wA1 * o1.z + wA2 * o2.z + wA3 * o3.z;
    acA3 += wA0 * o0.w + wA1 * o1.w + wA2 * o2.w + wA3 * o3.w;
    acB0 += wB0 * o0.x + wB1 * o1.x + wB2 * o2.x + wB3 * o3.x;
    acB1 += wB0 * o0.y + wB1 * o1.y + wB2 * o2.y + wB3 * o3.y;
    acB2 += wB0 * o0.z + wB1 * o1.z + wB2 * o2.z + wB3 * o3.z;
    acB3 += wB0 * o0.w + wB1 * o1.w + wB2 * o2.w + wB3 * o3.w;
  }
#pragma unroll
  for (int off = 32; off > 0; off >>= 1) {
    acA0 += __shfl_xor(acA0, off, 64); acA1 += __shfl_xor(acA1, off, 64);
    acA2 += __shfl_xor(acA2, off, 64); acA3 += __shfl_xor(acA3, off, 64);
    acB0 += __shfl_xor(acB0, off, 64); acB1 += __shfl_xor(acB1, off, 64);
    acB2 += __shfl_xor(acB2, off, 64); acB3 += __shfl_xor(acB3, off, 64);
  }
  if (g == 0) {
    calc[rowA * 4 + 0] = acA0; calc[rowA * 4 + 1] = acA1;
    calc[rowA * 4 + 2] = acA2; calc[rowA * 4 + 3] = acA3;
    calc[rowB * 4 + 0] = acB0; calc[rowB * 4 + 1] = acB1;
    calc[rowB * 4 + 2] = acB2; calc[rowB * 4 + 3] = acB3;
  }
}

// ---------------- kernel 6: gcn + mlp head --------------------------------
__global__ __launch_bounds__(64) void k_head(
    const float* __restrict__ calc, const float* __restrict__ gcn_w,
    const float* __restrict__ gcn_b, const float* __restrict__ gcn_a,
    const float* __restrict__ w1, const float* __restrict__ b1,
    const float* __restrict__ w2, const float* __restrict__ b2,
    float* __restrict__ out) {
  int row = blockIdx.x;
  int t = threadIdx.x;  // 64
  __shared__ float c4[4];
  __shared__ float gs[64];
  __shared__ float ms[32];
  if (t < 4) c4[t] = calc[row * 4 + t];
  __syncthreads();
  float g = gcn_b[t];
#pragma unroll
  for (int d = 0; d < 4; ++d) g += c4[d] * gcn_w[d * 64 + t];
  float ga = gcn_a[0];
  gs[t] = (g >= 0.f) ? g : ga * g;
  __syncthreads();
  if (t < 32) {
    float mm = b1[t];
#pragma unroll
    for (int i = 0; i < 64; ++i) mm += gs[i] * w1[i * 32 + t];
    ms[t] = fmaxf(mm, 0.f);
  }
  __syncthreads();
  if (t < 4) {
    float o = b2[t];
#pragma unroll
    for (int i = 0; i < 32; ++i) o += ms[i] * w2[i * 4 + t];
    out[row * 4 + t] = o;
  }
}

extern "C" void kernel_launch(void* const* d_in, const int* in_sizes, int n_in,
                              void* d_out, int out_size, void* d_ws, size_t ws_size,
                              hipStream_t stream) {
  (void)in_sizes; (void)n_in; (void)out_size; (void)ws_size;
  const float* inp    = (const float*)d_in[0];
  const float* emb_w  = (const float*)d_in[1];
  const float* emb_b  = (const float*)d_in[2];
  const float* q_w    = (const float*)d_in[3];
  const float* q_b    = (const float*)d_in[4];
  const float* k_w    = (const float*)d_in[5];
  const float* k_b    = (const float*)d_in[6];
  const float* conv_w1 = (const float*)d_in[7];
  const float* conv_w2 = (const float*)d_in[8];
  const float* conv_a  = (const float*)d_in[9];
  const float* gcn_w  = (const float*)d_in[10];
  const float* gcn_b  = (const float*)d_in[11];
  const float* gcn_a  = (const float*)d_in[12];
  const float* mlp_w1 = (const float*)d_in[13];
  const float* mlp_b1 = (const float*)d_in[14];
  const float* mlp_w2 = (const float*)d_in[15];
  const float* mlp_b2 = (const float*)d_in[16];
  float* out = (float*)d_out;

  const size_t NN = (size_t)NROWS * NROWS;
  float* A      = (float*)d_ws;              // 4096^2
  float* B      = A + NN;                    // 4096^2
  float* q      = B + NN;                    // 4096*64
  float* kT     = q + (size_t)NROWS * HID;   // 64*4096 (transposed)
  float* opk    = kT + (size_t)NROWS * HID;  // 4096*4
  float* rowmax = opk + (size_t)NROWS * 4;
  float* rowsum = rowmax + NROWS;
  float* calc   = rowsum + NROWS;            // 4096*4

  k_embed<<<NROWS, 64, 0, stream>>>(inp, emb_w, emb_b, q_w, q_b, k_w, k_b, q, kT, opk);
  k_scores<<<NROWS / 8, 256, 0, stream>>>(q, kT, A, rowmax);
  k_norm<<<NROWS / 8, 256, 0, stream>>>(A, rowmax, rowsum);

  float* cin = A;
  float* cout = B;
  for (int layer = 0; layer < 10; ++layer) {
    k_conv<<<dim3(NROWS / 256, NROWS / 8), 256, 0, stream>>>(cin, cout, conv_w1,
                                                             conv_w2, conv_a, layer);
    float* tmp = cin; cin = cout; cout = tmp;
  }
  // 10 swaps: final conv output back in A (== cin)

  k_calc<<<NROWS / 8, 256, 0, stream>>>(q, kT, cin, opk, rowmax, rowsum, calc);
  k_head<<<NROWS, 64, 0, stream>>>(calc, gcn_w, gcn_b, gcn_a, mlp_w1, mlp_b1,
                                   mlp_w2, mlp_b2, out);
}

// Round 3
// 627.180 us; speedup vs baseline: 1.8845x; 1.6887x over previous
//
#include <hip/hip_runtime.h>

#define NROWS 4096
#define HID 64

// ---------------- kernel 1: x=in@emb_w+b; q=x@q_w+b; kT=(x@k_w+b)^T; o pack
__global__ __launch_bounds__(64) void k_embed(
    const float* __restrict__ inp, const float* __restrict__ emb_w,
    const float* __restrict__ emb_b, const float* __restrict__ q_w,
    const float* __restrict__ q_b, const float* __restrict__ k_w,
    const float* __restrict__ k_b, float* __restrict__ q,
    float* __restrict__ kT, float* __restrict__ opk) {
  int row = blockIdx.x;
  int t = threadIdx.x;  // 64 threads
  __shared__ float in_s[8];
  __shared__ float x_s[64];
  if (t < 8) in_s[t] = inp[row * 8 + t];
  __syncthreads();
  float acc = emb_b[t];
#pragma unroll
  for (int i = 0; i < 8; ++i) acc += in_s[i] * emb_w[i * 64 + t];
  x_s[t] = acc;
  __syncthreads();
  float qa = q_b[t], ka = k_b[t];
#pragma unroll
  for (int i = 0; i < 64; ++i) {
    float xv = x_s[i];
    qa += xv * q_w[i * 64 + t];
    ka += xv * k_w[i * 64 + t];
  }
  q[row * 64 + t] = qa;
  kT[(size_t)t * NROWS + row] = ka;  // transposed store (tiny, one-off)
  if (t < 4) opk[row * 4 + t] = inp[row * 8 + 4 + t];
}

// ---------------- kernel 2: scores + full softmax (fused) -----------------
// 512 blocks x 256 thr. Wave p handles rows r0+p and r0+p+4 (full width).
// Per 256-col tile: block stages kT[64][256] into LDS, all waves consume.
// After: per-wave rowmax reduce, then 2 L2-hot passes (exp+sum, scale).
__global__ __launch_bounds__(256) void k_scores(
    const float* __restrict__ q, const float* __restrict__ kT,
    float* __restrict__ S, float* __restrict__ rowmax, float* __restrict__ rowsum) {
  __shared__ float kls[64][256];  // 64 KB
  int t = threadIdx.x;
  int p = t >> 6;
  int g = t & 63;
  int r0 = blockIdx.x * 8;
  int rowA = r0 + p, rowB = rowA + 4;
  float qa[64], qb[64];
  const float4* qA = (const float4*)(q + (size_t)rowA * 64);
  const float4* qB = (const float4*)(q + (size_t)rowB * 64);
#pragma unroll
  for (int i = 0; i < 16; ++i) {
    float4 v = qA[i];
    qa[4 * i] = v.x; qa[4 * i + 1] = v.y; qa[4 * i + 2] = v.z; qa[4 * i + 3] = v.w;
    float4 w = qB[i];
    qb[4 * i] = w.x; qb[4 * i + 1] = w.y; qb[4 * i + 2] = w.z; qb[4 * i + 3] = w.w;
  }
  float mA = -1e30f, mB = -1e30f;
  for (int tile = 0; tile < 16; ++tile) {
    __syncthreads();
#pragma unroll
    for (int it = 0; it < 16; ++it) {
      int c = it * 4 + p;
      float4 v = *(const float4*)(kT + (size_t)c * NROWS + tile * 256 + g * 4);
      *(float4*)(&kls[c][g * 4]) = v;
    }
    __syncthreads();
    float aA0 = 0.f, aA1 = 0.f, aA2 = 0.f, aA3 = 0.f;
    float aB0 = 0.f, aB1 = 0.f, aB2 = 0.f, aB3 = 0.f;
#pragma unroll
    for (int c = 0; c < 64; ++c) {
      float4 kv = *(float4*)(&kls[c][g * 4]);
      aA0 += qa[c] * kv.x; aA1 += qa[c] * kv.y; aA2 += qa[c] * kv.z; aA3 += qa[c] * kv.w;
      aB0 += qb[c] * kv.x; aB1 += qb[c] * kv.y; aB2 += qb[c] * kv.z; aB3 += qb[c] * kv.w;
    }
    int colb = tile * 256 + g * 4;
    aA0 *= 0.125f; aA1 *= 0.125f; aA2 *= 0.125f; aA3 *= 0.125f;
    aB0 *= 0.125f; aB1 *= 0.125f; aB2 *= 0.125f; aB3 *= 0.125f;
    float4 sA = {aA0, aA1, aA2, aA3};
    float4 sB = {aB0, aB1, aB2, aB3};
    *(float4*)(S + (size_t)rowA * NROWS + colb) = sA;
    *(float4*)(S + (size_t)rowB * NROWS + colb) = sB;
    mA = fmaxf(mA, fmaxf(fmaxf(aA0, aA1), fmaxf(aA2, aA3)));
    mB = fmaxf(mB, fmaxf(fmaxf(aB0, aB1), fmaxf(aB2, aB3)));
  }
#pragma unroll
  for (int off = 32; off > 0; off >>= 1) {
    mA = fmaxf(mA, __shfl_xor(mA, off, 64));
    mB = fmaxf(mB, __shfl_xor(mB, off, 64));
  }
  // pass 2: exp + sum (rows are wave-private; L2-hot)
  float4* SA = (float4*)(S + (size_t)rowA * NROWS);
  float4* SB = (float4*)(S + (size_t)rowB * NROWS);
  float sA = 0.f, sB = 0.f;
  for (int i = g; i < 1024; i += 64) {
    float4 v = SA[i];
    v.x = __expf(v.x - mA); v.y = __expf(v.y - mA);
    v.z = __expf(v.z - mA); v.w = __expf(v.w - mA);
    SA[i] = v;
    sA += v.x + v.y + v.z + v.w;
    float4 w = SB[i];
    w.x = __expf(w.x - mB); w.y = __expf(w.y - mB);
    w.z = __expf(w.z - mB); w.w = __expf(w.w - mB);
    SB[i] = w;
    sB += w.x + w.y + w.z + w.w;
  }
#pragma unroll
  for (int off = 32; off > 0; off >>= 1) {
    sA += __shfl_xor(sA, off, 64);
    sB += __shfl_xor(sB, off, 64);
  }
  float liA = 1.0f / sA, liB = 1.0f / sB;
  // pass 3: scale (L2-hot)
  for (int i = g; i < 1024; i += 64) {
    float4 v = SA[i];
    v.x *= liA; v.y *= liA; v.z *= liA; v.w *= liA;
    SA[i] = v;
    float4 w = SB[i];
    w.x *= liB; w.y *= liB; w.z *= liB; w.w *= liB;
    SB[i] = w;
  }
  if (g == 0) {
    rowmax[rowA] = mA; rowsum[rowA] = sA;
    rowmax[rowB] = mB; rowsum[rowB] = sB;
  }
}

// ---------------- kernel 4: one asym conv layer + leaky relu --------------
__global__ __launch_bounds__(256) void k_conv(
    const float* __restrict__ in, float* __restrict__ out,
    const float* __restrict__ w1p, const float* __restrict__ w2p,
    const float* __restrict__ ap, int layer) {
  float w10 = w1p[layer * 3], w11 = w1p[layer * 3 + 1], w12 = w1p[layer * 3 + 2];
  float w20 = w2p[layer * 3], w21 = w2p[layer * 3 + 1], w22 = w2p[layer * 3 + 2];
  float a = ap[layer];
  int j = blockIdx.x * 256 + threadIdx.x;
  int i0 = blockIdx.y * 8;
  float vm = (i0 > 0) ? in[(size_t)(i0 - 1) * NROWS + j] : 0.f;
  float vc = in[(size_t)i0 * NROWS + j];
#pragma unroll
  for (int rr = 0; rr < 8; ++rr) {
    int i = i0 + rr;
    float vp = (i + 1 < NROWS) ? in[(size_t)(i + 1) * NROWS + j] : 0.f;
    float lft = (j > 0) ? in[(size_t)i * NROWS + j - 1] : 0.f;
    float rgt = (j < NROWS - 1) ? in[(size_t)i * NROWS + j + 1] : 0.f;
    float o = w10 * lft + w11 * vc + w12 * rgt + w20 * vm + w21 * vc + w22 * vp;
    out[(size_t)i * NROWS + j] = (o >= 0.f) ? o : a * o;
    vm = vc;
    vc = vp;
  }
}

// ---------------- kernel 5: calc = (conv>0)*softmax(s) @ o (recompute) ----
// Same LDS-staged kT structure as k_scores.
__global__ __launch_bounds__(256) void k_calc(
    const float* __restrict__ q, const float* __restrict__ kT,
    const float* __restrict__ conv, const float* __restrict__ opk,
    const float* __restrict__ rowmax, const float* __restrict__ rowsum,
    float* __restrict__ calc) {
  __shared__ float kls[64][256];  // 64 KB
  int t = threadIdx.x;
  int p = t >> 6;
  int g = t & 63;
  int r0 = blockIdx.x * 8;
  int rowA = r0 + p, rowB = rowA + 4;
  float qa[64], qb[64];
  const float4* qA = (const float4*)(q + (size_t)rowA * 64);
  const float4* qB = (const float4*)(q + (size_t)rowB * 64);
#pragma unroll
  for (int i = 0; i < 16; ++i) {
    float4 v = qA[i];
    qa[4 * i] = v.x; qa[4 * i + 1] = v.y; qa[4 * i + 2] = v.z; qa[4 * i + 3] = v.w;
    float4 w = qB[i];
    qb[4 * i] = w.x; qb[4 * i + 1] = w.y; qb[4 * i + 2] = w.z; qb[4 * i + 3] = w.w;
  }
  float mA = rowmax[rowA], liA = 1.0f / rowsum[rowA];
  float mB = rowmax[rowB], liB = 1.0f / rowsum[rowB];
  float acA0 = 0.f, acA1 = 0.f, acA2 = 0.f, acA3 = 0.f;
  float acB0 = 0.f, acB1 = 0.f, acB2 = 0.f, acB3 = 0.f;
  for (int tile = 0; tile < 16; ++tile) {
    __syncthreads();
#pragma unroll
    for (int it = 0; it < 16; ++it) {
      int c = it * 4 + p;
      float4 v = *(const float4*)(kT + (size_t)c * NROWS + tile * 256 + g * 4);
      *(float4*)(&kls[c][g * 4]) = v;
    }
    __syncthreads();
    float aA0 = 0.f, aA1 = 0.f, aA2 = 0.f, aA3 = 0.f;
    float aB0 = 0.f, aB1 = 0.f, aB2 = 0.f, aB3 = 0.f;
#pragma unroll
    for (int c = 0; c < 64; ++c) {
      float4 kv = *(float4*)(&kls[c][g * 4]);
      aA0 += qa[c] * kv.x; aA1 += qa[c] * kv.y; aA2 += qa[c] * kv.z; aA3 += qa[c] * kv.w;
      aB0 += qb[c] * kv.x; aB1 += qb[c] * kv.y; aB2 += qb[c] * kv.z; aB3 += qb[c] * kv.w;
    }
    int colb = tile * 256 + g * 4;
    float4 cA = *(const float4*)(conv + (size_t)rowA * NROWS + colb);
    float4 cB = *(const float4*)(conv + (size_t)rowB * NROWS + colb);
    const float4* op = (const float4*)opk + colb;
    float4 o0 = op[0], o1 = op[1], o2 = op[2], o3 = op[3];
    float wA0 = (cA.x > 0.f) ? __expf(aA0 * 0.125f - mA) * liA : 0.f;
    float wA1 = (cA.y > 0.f) ? __expf(aA1 * 0.125f - mA) * liA : 0.f;
    float wA2 = (cA.z > 0.f) ? __expf(aA2 * 0.125f - mA) * liA : 0.f;
    float wA3 = (cA.w > 0.f) ? __expf(aA3 * 0.125f - mA) * liA : 0.f;
    float wB0 = (cB.x > 0.f) ? __expf(aB0 * 0.125f - mB) * liB : 0.f;
    float wB1 = (cB.y > 0.f) ? __expf(aB1 * 0.125f - mB) * liB : 0.f;
    float wB2 = (cB.z > 0.f) ? __expf(aB2 * 0.125f - mB) * liB : 0.f;
    float wB3 = (cB.w > 0.f) ? __expf(aB3 * 0.125f - mB) * liB : 0.f;
    acA0 += wA0 * o0.x + wA1 * o1.x + wA2 * o2.x + wA3 * o3.x;
    acA1 += wA0 * o0.y + wA1 * o1.y + wA2 * o2.y + wA3 * o3.y;
    acA2 += wA0 * o0.z + wA1 * o1.z + wA2 * o2.z + wA3 * o3.z;
    acA3 += wA0 * o0.w + wA1 * o1.w + wA2 * o2.w + wA3 * o3.w;
    acB0 += wB0 * o0.x + wB1 * o1.x + wB2 * o2.x + wB3 * o3.x;
    acB1 += wB0 * o0.y + wB1 * o1.y + wB2 * o2.y + wB3 * o3.y;
    acB2 += wB0 * o0.z + wB1 * o1.z + wB2 * o2.z + wB3 * o3.z;
    acB3 += wB0 * o0.w + wB1 * o1.w + wB2 * o2.w + wB3 * o3.w;
  }
#pragma unroll
  for (int off = 32; off > 0; off >>= 1) {
    acA0 += __shfl_xor(acA0, off, 64); acA1 += __shfl_xor(acA1, off, 64);
    acA2 += __shfl_xor(acA2, off, 64); acA3 += __shfl_xor(acA3, off, 64);
    acB0 += __shfl_xor(acB0, off, 64); acB1 += __shfl_xor(acB1, off, 64);
    acB2 += __shfl_xor(acB2, off, 64); acB3 += __shfl_xor(acB3, off, 64);
  }
  if (g == 0) {
    calc[rowA * 4 + 0] = acA0; calc[rowA * 4 + 1] = acA1;
    calc[rowA * 4 + 2] = acA2; calc[rowA * 4 + 3] = acA3;
    calc[rowB * 4 + 0] = acB0; calc[rowB * 4 + 1] = acB1;
    calc[rowB * 4 + 2] = acB2; calc[rowB * 4 + 3] = acB3;
  }
}

// ---------------- kernel 6: gcn + mlp head --------------------------------
__global__ __launch_bounds__(64) void k_head(
    const float* __restrict__ calc, const float* __restrict__ gcn_w,
    const float* __restrict__ gcn_b, const float* __restrict__ gcn_a,
    const float* __restrict__ w1, const float* __restrict__ b1,
    const float* __restrict__ w2, const float* __restrict__ b2,
    float* __restrict__ out) {
  int row = blockIdx.x;
  int t = threadIdx.x;  // 64
  __shared__ float c4[4];
  __shared__ float gs[64];
  __shared__ float ms[32];
  if (t < 4) c4[t] = calc[row * 4 + t];
  __syncthreads();
  float g = gcn_b[t];
#pragma unroll
  for (int d = 0; d < 4; ++d) g += c4[d] * gcn_w[d * 64 + t];
  float ga = gcn_a[0];
  gs[t] = (g >= 0.f) ? g : ga * g;
  __syncthreads();
  if (t < 32) {
    float mm = b1[t];
#pragma unroll
    for (int i = 0; i < 64; ++i) mm += gs[i] * w1[i * 32 + t];
    ms[t] = fmaxf(mm, 0.f);
  }
  __syncthreads();
  if (t < 4) {
    float o = b2[t];
#pragma unroll
    for (int i = 0; i < 32; ++i) o += ms[i] * w2[i * 4 + t];
    out[row * 4 + t] = o;
  }
}

extern "C" void kernel_launch(void* const* d_in, const int* in_sizes, int n_in,
                              void* d_out, int out_size, void* d_ws, size_t ws_size,
                              hipStream_t stream) {
  (void)in_sizes; (void)n_in; (void)out_size; (void)ws_size;
  const float* inp    = (const float*)d_in[0];
  const float* emb_w  = (const float*)d_in[1];
  const float* emb_b  = (const float*)d_in[2];
  const float* q_w    = (const float*)d_in[3];
  const float* q_b    = (const float*)d_in[4];
  const float* k_w    = (const float*)d_in[5];
  const float* k_b    = (const float*)d_in[6];
  const float* conv_w1 = (const float*)d_in[7];
  const float* conv_w2 = (const float*)d_in[8];
  const float* conv_a  = (const float*)d_in[9];
  const float* gcn_w  = (const float*)d_in[10];
  const float* gcn_b  = (const float*)d_in[11];
  const float* gcn_a  = (const float*)d_in[12];
  const float* mlp_w1 = (const float*)d_in[13];
  const float* mlp_b1 = (const float*)d_in[14];
  const float* mlp_w2 = (const float*)d_in[15];
  const float* mlp_b2 = (const float*)d_in[16];
  float* out = (float*)d_out;

  const size_t NN = (size_t)NROWS * NROWS;
  float* A      = (float*)d_ws;              // 4096^2
  float* B      = A + NN;                    // 4096^2
  float* q      = B + NN;                    // 4096*64
  float* kT     = q + (size_t)NROWS * HID;   // 64*4096 (transposed)
  float* opk    = kT + (size_t)NROWS * HID;  // 4096*4
  float* rowmax = opk + (size_t)NROWS * 4;
  float* rowsum = rowmax + NROWS;
  float* calc   = rowsum + NROWS;            // 4096*4

  k_embed<<<NROWS, 64, 0, stream>>>(inp, emb_w, emb_b, q_w, q_b, k_w, k_b, q, kT, opk);
  k_scores<<<NROWS / 8, 256, 0, stream>>>(q, kT, A, rowmax, rowsum);

  float* cin = A;
  float* cout = B;
  for (int layer = 0; layer < 10; ++layer) {
    k_conv<<<dim3(NROWS / 256, NROWS / 8), 256, 0, stream>>>(cin, cout, conv_w1,
                                                             conv_w2, conv_a, layer);
    float* tmp = cin; cin = cout; cout = tmp;
  }
  // 10 swaps: final conv output back in A (== cin)

  k_calc<<<NROWS / 8, 256, 0, stream>>>(q, kT, cin, opk, rowmax, rowsum, calc);
  k_head<<<NROWS, 64, 0, stream>>>(calc, gcn_w, gcn_b, gcn_a, mlp_w1, mlp_b1,
                                   mlp_w2, mlp_b2, out);
}